// Round 12
// baseline (192.541 us; speedup 1.0000x reference)
//
#include <hip/hip_runtime.h>
#include <hip/hip_bf16.h>

#define D_MODEL 1024
#define NHEAD   16
#define HDIM    64
#define SEQQ    2048
#define NBATCH  2
#define MROWS   (NBATCH * SEQQ)   // 4096

typedef unsigned short u16;
typedef __attribute__((ext_vector_type(8))) short short8;    // 8 bf16 (4 VGPRs)
typedef __attribute__((ext_vector_type(4))) short bf16x4;    // 4 bf16 (2 VGPRs)
typedef __attribute__((ext_vector_type(4))) float floatx4;   // 4 fp32

__device__ __forceinline__ u16 f2b(float f) {
    union { __hip_bfloat16 h; u16 u; } cv;
    cv.h = __float2bfloat16(f);
    return cv.u;
}
__device__ __forceinline__ float b2f(u16 u) {
    return __uint_as_float(((unsigned int)u) << 16);
}
__device__ __forceinline__ short8 load8(const u16* p) {
    return *reinterpret_cast<const short8*>(p);
}
__device__ __forceinline__ bf16x4 load4v(const u16* p) {
    return *reinterpret_cast<const bf16x4*>(p);
}
__device__ __forceinline__ unsigned pack2(float lo, float hi) {
    return ((unsigned)f2b(hi) << 16) | (unsigned)f2b(lo);
}
__device__ __forceinline__ void async_cp16(const void* g, void* l) {
    __builtin_amdgcn_global_load_lds(
        (const __attribute__((address_space(1))) void*)g,
        (__attribute__((address_space(3))) void*)l, 16, 0, 0);
}

// ---------------- fp32 -> bf16 convert + RoPE cos/sin table, one dispatch ----------------
// z 0..3: X quarters (flat). z 4..5: Wq/Wk with per-head row DE-INTERLEAVE
// (out row position q<32 of a head holds feature 2q; position 32+q holds
// feature 2q+1) -> rope partners land in the SAME LANE, adjacent n-frag, in
// the gemm epilogue. z=6..7: Wv/Wo flat. z=8: rope table tab[j*SEQQ+s]=(cos,sin).
__global__ void cvt_all(const float* __restrict__ X,
                        const float* __restrict__ w0, const float* __restrict__ w1,
                        const float* __restrict__ w2, const float* __restrict__ w3,
                        const int* __restrict__ pos,
                        u16* __restrict__ xo,
                        u16* __restrict__ o0, u16* __restrict__ o1,
                        u16* __restrict__ o2, u16* __restrict__ o3,
                        float2* __restrict__ tab) {
    const int z = blockIdx.y;
    const int i = blockIdx.x * 256 + threadIdx.x;
    if (z == 8) {
        if (i < SEQQ * 32) {
            const int j = i >> 11, s = i & (SEQQ - 1);
            const float p = (float)pos[s];
            const float inv = expf(-(float)j * (9.210340371976184f / 32.0f));
            float sn, cs;
            sincosf(p * inv, &sn, &cs);
            tab[i] = make_float2(cs, sn);
        }
        return;
    }
    const int n4 = (D_MODEL * D_MODEL) / 4;
    const float* in;
    u16* out;
    if (z < 4) { in = X + (size_t)z * n4 * 4;  out = xo + (size_t)z * n4 * 4; }
    else {
        in  = (z == 4) ? w0 : (z == 5) ? w1 : (z == 6) ? w2 : w3;
        out = (z == 4) ? o0 : (z == 5) ? o1 : (z == 6) ? o2 : o3;
    }
    int src = i;
    if (z == 4 || z == 5) {
        const int orow = i >> 8;            // out weight row (256 float4 / row)
        const int g    = i & 255;
        const int irow = (orow & ~63) | (((orow & 31) << 1) | ((orow >> 5) & 1));
        src = irow * 256 + g;
    }
    float4 v = reinterpret_cast<const float4*>(in)[src];
    ushort4 o;
    o.x = f2b(v.x); o.y = f2b(v.y); o.z = f2b(v.z); o.w = f2b(v.w);
    reinterpret_cast<ushort4*>(out)[i] = o;
}

// ---------------- QKV GEMM v8: 256x256 tile, phase-interleaved 4-slot pipeline ----------------
// R8-R11 falsified vmcnt/swizzle/occupancy/amortization/instr-count on the
// 2-phase schedule: the ~50us is the 2-phase stage+drain+barrier structure
// itself (guide m233: ~72% overhead; T2/T4 null at 2ph, m218/m252). v8 ports
// the phase-interleave (T3+T4): 512 threads (8 waves 2x4), K-half granularity.
// LDS = 4 rotating slots, each one K-half (A 256x32 + B 256x32, 32 KB);
// half h lives in slot h&3. Phase q (0..31): stage half q+3 into slot
// (q+3)&3 (dead: its last readers finished at phase q-1's end barrier);
// read 12 frags from slot q&3; vmcnt(8) = guarantee half q+1 while keeping
// the newest 8 loads (halves q+2,q+3) in flight -- NEVER drains in steady
// state; barrier; 32 MFMA; barrier. Uniform 3-phase issue-to-use distance.
// Tail: vmcnt 8/4/0 at q=28/29/30+ (FIFO retirement makes this exact).
// Slot rows are 64 B -> fragment reads natively 2-way bank-aliased (free,
// m136) -> no swizzle needed. Fused epilogues carried over (2x4 wave grid:
// head = tn/64 + wc; rope partner = acc[m][n+2], same lane).
__global__ __launch_bounds__(512, 2) void gemm_qkv(
    const u16* __restrict__ A,
    const u16* __restrict__ B0, const u16* __restrict__ B1, const u16* __restrict__ B2,
    u16* __restrict__ Qt, u16* __restrict__ Kt, u16* __restrict__ Vt,
    const float2* __restrict__ tab)
{
    const int K = D_MODEL;
    const int z = blockIdx.z;
    const u16* Bt = (z == 0) ? B0 : (z == 1 ? B1 : B2);

    __shared__ __attribute__((aligned(16))) u16 As[4][256 * 32];   // 64 KB
    __shared__ __attribute__((aligned(16))) u16 Bs[4][256 * 32];   // 64 KB

    const int tid  = threadIdx.x;
    const int w    = tid >> 6;          // 0..7
    const int lane = tid & 63;
    const int l15  = lane & 15;
    const int quad = lane >> 4;
    const int wr   = w >> 2;            // 0..1  (128 output rows each)
    const int wc   = w & 3;             // 0..3  (64 output cols each = one head)
    const int tm   = blockIdx.x * 256, tn = blockIdx.y * 256;

    floatx4 acc[8][4];
#pragma unroll
    for (int m = 0; m < 8; m++)
#pragma unroll
        for (int n = 0; n < 4; n++) {
            floatx4 z4 = {0.f, 0.f, 0.f, 0.f};
            acc[m][n] = z4;
        }

    // stage one K-half hh (tile hh>>1, k-half hh&1) into slot hh&3.
    // per wave: rows w*32..w*32+31 of both A and B; 2 calls each (16 rows/call,
    // lane -> row lane>>2, 16B chunk lane&3). 4 loads/thread/half.
    const int srow = lane >> 2;         // 0..15
    const int sc8  = (lane & 3) * 8;    // 0,8,16,24 elements
    auto stageH = [&](int hh) {
        const int kb = (hh >> 1) * 64 + (hh & 1) * 32;
        const int sl = hh & 3;
        const int r0 = w * 32 + srow;
        async_cp16(A  + (size_t)(tm + r0) * K + kb + sc8,      &As[sl][(w * 32) * 32]);
        async_cp16(A  + (size_t)(tm + r0 + 16) * K + kb + sc8, &As[sl][(w * 32 + 16) * 32]);
        async_cp16(Bt + (size_t)(tn + r0) * K + kb + sc8,      &Bs[sl][(w * 32) * 32]);
        async_cp16(Bt + (size_t)(tn + r0 + 16) * K + kb + sc8, &Bs[sl][(w * 32 + 16) * 32]);
    };

    // prologue: halves 0,1,2 resident/inflight; guarantee half 0 (8 newer in flight)
    stageH(0); stageH(1); stageH(2);
    asm volatile("s_waitcnt vmcnt(8)" ::: "memory");
    __builtin_amdgcn_s_barrier();

    for (int q = 0; q < 32; ++q) {
        if (q + 3 < 32) stageH(q + 3);   // slot (q+3)&3: last read at phase q-1, barrier-sep

        const u16* Aslot = &As[q & 3][0];
        const u16* Bslot = &Bs[q & 3][0];
        short8 af[8], bf[4];
#pragma unroll
        for (int m = 0; m < 8; m++)
            af[m] = load8(&Aslot[(wr * 128 + m * 16 + l15) * 32 + quad * 8]);
#pragma unroll
        for (int n = 0; n < 4; n++)
            bf[n] = load8(&Bslot[(wc * 64 + n * 16 + l15) * 32 + quad * 8]);

        // guarantee half q+1 for next phase's reads; keep halves q+2,q+3 in flight
        if (q <= 28)      asm volatile("s_waitcnt vmcnt(8)" ::: "memory");
        else if (q == 29) asm volatile("s_waitcnt vmcnt(4)" ::: "memory");
        else              asm volatile("s_waitcnt vmcnt(0)" ::: "memory");
        __builtin_amdgcn_s_barrier();

        __builtin_amdgcn_s_setprio(1);
#pragma unroll
        for (int m = 0; m < 8; m++)
#pragma unroll
            for (int n = 0; n < 4; n++)
                acc[m][n] = __builtin_amdgcn_mfma_f32_16x16x32_bf16(af[m], bf[n], acc[m][n], 0, 0, 0);
        __builtin_amdgcn_s_setprio(0);
        __builtin_amdgcn_s_barrier();
    }

    const int hh = (tn >> 6) + wc;      // head index (wave owns one full head)

    if (z == 2) {
        // V: write transposed [b,h,d,s]; 4 rg = 4 consecutive s, one 8B store
#pragma unroll
        for (int m = 0; m < 8; m++) {
            const int r0 = tm + wr * 128 + m * 16 + quad * 4;
            const int bb = r0 >> 11, s0 = r0 & (SEQQ - 1);
#pragma unroll
            for (int n = 0; n < 4; n++) {
                const int d = n * 16 + l15;
                ushort4 pk;
                pk.x = f2b(acc[m][n][0]);
                pk.y = f2b(acc[m][n][1]);
                pk.z = f2b(acc[m][n][2]);
                pk.w = f2b(acc[m][n][3]);
                *reinterpret_cast<ushort4*>(
                    &Vt[(((size_t)(bb * NHEAD + hh)) * HDIM + d) * SEQQ + s0]) = pk;
            }
        }
    } else {
        // Q/K rope: de-interleaved -> partner = acc[m][n+2], same lane.
        const float qsc = (z == 0) ? 0.18033688011112042f : 1.0f;  // 0.125*log2(e) | 1
        u16* Outp = (z == 0) ? Qt : Kt;
        float4 ta[2], tb[2];
        auto ldtab = [&](int g) {
            const int m = g >> 1, n = g & 1;
            const int qq = n * 16 + l15;
            const int s0 = (tm + wr * 128 + m * 16 + quad * 4) & (SEQQ - 1);
            ta[g & 1] = *reinterpret_cast<const float4*>(&tab[qq * SEQQ + s0]);
            tb[g & 1] = *reinterpret_cast<const float4*>(&tab[qq * SEQQ + s0 + 2]);
        };
        ldtab(0);
#pragma unroll
        for (int g = 0; g < 16; ++g) {
            if (g < 15) ldtab(g + 1);       // issue next group's loads early
            const int m = g >> 1, n = g & 1;
            const int qq = n * 16 + l15;
            const int r0 = tm + wr * 128 + m * 16 + quad * 4;
            const int bb = r0 >> 11, s0 = r0 & (SEQQ - 1);
            const float4 A4 = ta[g & 1], B4 = tb[g & 1];
            const float cs[4] = {A4.x, A4.z, B4.x, B4.z};
            const float sn[4] = {A4.y, A4.w, B4.y, B4.w};
#pragma unroll
            for (int j = 0; j < 4; j++) {
                const float e = acc[m][n][j];
                const float o = acc[m][n + 2][j];
                const unsigned val =
                    (unsigned)f2b((e * cs[j] - o * sn[j]) * qsc) |
                    ((unsigned)f2b((e * sn[j] + o * cs[j]) * qsc) << 16);
                *reinterpret_cast<unsigned*>(
                    &Outp[(((size_t)(bb * NHEAD + hh)) * SEQQ + (s0 + j)) * HDIM + 2 * qq]) = val;
            }
        }
    }
}

// ---------------- causal flash attention v13 (unchanged, best-known) ----------------
__global__ __launch_bounds__(256, 4) void attn_kernel(
    const u16* __restrict__ Qt, const u16* __restrict__ Kt, const u16* __restrict__ Vt,
    u16* __restrict__ Out)
{
    const int bid = blockIdx.x;
    const int xcd = bid & 7;
    const int u   = bid >> 3;               // 0..127 within XCD
    const int col = xcd * 4 + (u & 3);      // (b,h) column 0..31, 4 per XCD
    const int m   = u >> 2;                 // 0..31
    int qsub;
    if      (m < 8)  qsub = 31 - m;
    else if (m < 16) qsub = m - 8;
    else if (m < 24) qsub = 39 - m;
    else             qsub = m - 16;
    const int h = col & (NHEAD - 1), b = col >> 4;

    const int tid = threadIdx.x, w = tid >> 6, lane = tid & 63;
    const int l15 = lane & 15, quad = lane >> 4;
    const size_t bh = (size_t)(b * NHEAD + h);
    const u16* Qh = Qt + bh * SEQQ * HDIM;
    const u16* Kh = Kt + bh * SEQQ * HDIM;
    const u16* Vh = Vt + bh * HDIM * SEQQ;   // [d][s]

    __shared__ __attribute__((aligned(16))) u16 Ks[2][64 * 64];   // 16 KB
    __shared__ __attribute__((aligned(16))) u16 Vs[2][64 * 64];   // 16 KB

    short8 ones;
#pragma unroll
    for (int i = 0; i < 8; i++) ones[i] = (short)0x3F80;  // bf16 1.0

    // staging: each of 4 waves stages 2 K-chunks + 2 V-chunks (1 KB each)
    const int rr  = lane >> 3;                 // 0..7
    const int swz = ((lane & 7) ^ rr) * 8;     // XOR-swizzled col offset (u16)
    auto stage = [&](int buf, int tt) {
        const int k0s = tt * 64;
        async_cp16(Kh + (size_t)(k0s + w * 8 + rr) * HDIM + swz,       &Ks[buf][w * 512]);
        async_cp16(Kh + (size_t)(k0s + (w + 4) * 8 + rr) * HDIM + swz, &Ks[buf][(w + 4) * 512]);
        async_cp16(Vh + (size_t)(w * 8 + rr) * SEQQ + k0s + swz,       &Vs[buf][w * 512]);
        async_cp16(Vh + (size_t)((w + 4) * 8 + rr) * SEQQ + k0s + swz, &Vs[buf][(w + 4) * 512]);
    };

    const int s7  = l15 & 7;
    const int sw1 = ((quad)     ^ s7) * 8;     // K dims chunk 0..31
    const int sw2 = ((quad + 4) ^ s7) * 8;     // K dims chunk 32..63
    // V b64 element offsets for permuted PV k-slots (chunk*8 + (quad&1)*4):
    const int vo0 = (((quad >> 1)    ) ^ s7) * 8 + (quad & 1) * 4;  // keys  4*quad..
    const int vo1 = (((quad >> 1) + 2) ^ s7) * 8 + (quad & 1) * 4;  // keys 16+4*quad..
    const int vo2 = (((quad >> 1) + 4) ^ s7) * 8 + (quad & 1) * 4;  // keys 32+4*quad..
    const int vo3 = (((quad >> 1) + 6) ^ s7) * 8 + (quad & 1) * 4;  // keys 48+4*quad..

    const int q0w   = qsub * 64 + w * 16;      // this wave's 16 q-rows
    const int tmaxp = qsub;                    // diag tile, same for all 4 waves

    // Q fragment loads FIRST (drained together with stage(0) by first vmcnt(0))
    short8 qf[2];
#pragma unroll
    for (int kk = 0; kk < 2; kk++)
        qf[kk] = load8(&Qh[(size_t)(q0w + l15) * HDIM + kk * 32 + quad * 8]);

    floatx4 O[4];
    floatx4 l_acc = {0.f, 0.f, 0.f, 0.f};
#pragma unroll
    for (int c = 0; c < 4; c++) { floatx4 zz = {0.f, 0.f, 0.f, 0.f}; O[c] = zz; }

    stage(0, 0);

    for (int t = 0; t <= tmaxp; ++t) {
        // stage(t) (4 DMAs, issued one full tile-compute ago) must be complete
        asm volatile("s_waitcnt vmcnt(0)" ::: "memory");
        __builtin_amdgcn_s_barrier();
        if (t < tmaxp) stage((t + 1) & 1, t + 1);   // prefetch distance 1

        const u16* KsB = &Ks[t & 1][0];
        const u16* VsB = &Vs[t & 1][0];
        const int k0 = t * 64;

        // S^T[c]: rows = key_local (c*16 + quad*4 + r), cols = q (l15)
        floatx4 S[4];
        __builtin_amdgcn_s_setprio(1);
#pragma unroll
        for (int c = 0; c < 4; c++) {
            const int rowb = (c * 16 + l15) * 64;
            floatx4 zz = {0.f, 0.f, 0.f, 0.f};
            S[c] = __builtin_amdgcn_mfma_f32_16x16x32_bf16(load8(&KsB[rowb + sw1]), qf[0], zz,   0, 0, 0);
            S[c] = __builtin_amdgcn_mfma_f32_16x16x32_bf16(load8(&KsB[rowb + sw2]), qf[1], S[c], 0, 0, 0);
        }
        __builtin_amdgcn_s_setprio(0);

        if (t == tmaxp) {
            const int q = q0w + l15;
#pragma unroll
            for (int c = 0; c < 4; c++)
#pragma unroll
                for (int r = 0; r < 4; r++)
                    if (k0 + c * 16 + quad * 4 + r > q) S[c][r] = -1e30f;
        }

#pragma unroll
        for (int c = 0; c < 4; c++)
#pragma unroll
            for (int r = 0; r < 4; r++)
                S[c][r] = __builtin_amdgcn_exp2f(S[c][r]);

        // ---- pack P into PV A-fragments (lane-local, permuted k-slots) ----
        union { short8 v; unsigned u[4]; } pf0, pf1;
        pf0.u[0] = pack2(S[0][0], S[0][1]);
        pf0.u[1] = pack2(S[0][2], S[0][3]);
        pf0.u[2] = pack2(S[1][0], S[1][1]);
        pf0.u[3] = pack2(S[1][2], S[1][3]);
        pf1.u[0] = pack2(S[2][0], S[2][1]);
        pf1.u[1] = pack2(S[2][2], S[2][3]);
        pf1.u[2] = pack2(S[3][0], S[3][1]);
        pf1.u[3] = pack2(S[3][2], S[3][3]);

        __builtin_amdgcn_s_setprio(1);
        l_acc = __builtin_amdgcn_mfma_f32_16x16x32_bf16(pf0.v, ones, l_acc, 0, 0, 0);
        l_acc = __builtin_amdgcn_mfma_f32_16x16x32_bf16(pf1.v, ones, l_acc, 0, 0, 0);

#pragma unroll
        for (int c2 = 0; c2 < 4; c2++) {
            const int rowb = (c2 * 16 + l15) * 64;
            bf16x4 a0 = load4v(&VsB[rowb + vo0]);
            bf16x4 a1 = load4v(&VsB[rowb + vo1]);
            bf16x4 a2 = load4v(&VsB[rowb + vo2]);
            bf16x4 a3 = load4v(&VsB[rowb + vo3]);
            short8 v0 = __builtin_shufflevector(a0, a1, 0, 1, 2, 3, 4, 5, 6, 7);
            short8 v1 = __builtin_shufflevector(a2, a3, 0, 1, 2, 3, 4, 5, 6, 7);
            O[c2] = __builtin_amdgcn_mfma_f32_16x16x32_bf16(pf0.v, v0, O[c2], 0, 0, 0);
            O[c2] = __builtin_amdgcn_mfma_f32_16x16x32_bf16(pf1.v, v1, O[c2], 0, 0, 0);
        }
        __builtin_amdgcn_s_setprio(0);
    }

    float inv_l[4];
#pragma unroll
    for (int r = 0; r < 4; r++) inv_l[r] = 1.0f / l_acc[r];

#pragma unroll
    for (int c2 = 0; c2 < 4; c2++)
#pragma unroll
        for (int r = 0; r < 4; r++) {
            const int q    = q0w + quad * 4 + r;
            const int colo = h * HDIM + c2 * 16 + l15;
            Out[(size_t)(b * SEQQ + q) * D_MODEL + colo] = f2b(O[c2][r] * inv_l[r]);
        }
}

// ---------------- o-proj GEMM: 64x64 tile, 1024 blocks, 16x16 MFMA (best-known) ----------------
__global__ __launch_bounds__(256) void gemm_o(
    const u16* __restrict__ A, const u16* __restrict__ Bt, float* __restrict__ C)
{
    const int K = D_MODEL, N = D_MODEL;
    __shared__ __attribute__((aligned(16))) u16 As[3][64 * 32];
    __shared__ __attribute__((aligned(16))) u16 Bs[3][64 * 32];

    const int tid  = threadIdx.x;
    const int w    = tid >> 6;
    const int lane = tid & 63;
    const int l15  = lane & 15;
    const int quad = lane >> 4;
    const int wm   = w >> 1, wn = w & 1;
    const int tm   = blockIdx.x * 64, tn = blockIdx.y * 64;

    floatx4 acc[2][2];
#pragma unroll
    for (int i = 0; i < 2; i++)
#pragma unroll
        for (int j = 0; j < 2; j++) {
            floatx4 z = {0.f, 0.f, 0.f, 0.f};
            acc[i][j] = z;
        }

    const int srow = lane >> 2;
    const int scol = (lane & 3) * 8;

    auto stage = [&](int buf, int k0) {
        async_cp16(A  + (size_t)(tm + w * 16 + srow) * K + k0 + scol, &As[buf][w * 512]);
        async_cp16(Bt + (size_t)(tn + w * 16 + srow) * K + k0 + scol, &Bs[buf][w * 512]);
    };

    stage(0, 0);
    stage(1, 32);

    for (int kt = 0; kt < 32; ++kt) {
        if (kt < 30) asm volatile("s_waitcnt vmcnt(2)" ::: "memory");
        else         asm volatile("s_waitcnt vmcnt(0)" ::: "memory");
        __builtin_amdgcn_s_barrier();
        if (kt < 30) stage((kt + 2) % 3, (kt + 2) * 32);

        const u16* AsB = &As[kt % 3][0];
        const u16* BsB = &Bs[kt % 3][0];

        short8 af[2], bfr[2];
#pragma unroll
        for (int mi = 0; mi < 2; mi++)
            af[mi] = load8(&AsB[(wm * 32 + mi * 16 + l15) * 32 + quad * 8]);
#pragma unroll
        for (int ni = 0; ni < 2; ni++)
            bfr[ni] = load8(&BsB[(wn * 32 + ni * 16 + l15) * 32 + quad * 8]);
#pragma unroll
        for (int mi = 0; mi < 2; mi++)
#pragma unroll
            for (int ni = 0; ni < 2; ni++)
                acc[mi][ni] = __builtin_amdgcn_mfma_f32_16x16x32_bf16(af[mi], bfr[ni], acc[mi][ni], 0, 0, 0);
    }

#pragma unroll
    for (int mi = 0; mi < 2; mi++)
#pragma unroll
        for (int ni = 0; ni < 2; ni++)
#pragma unroll
            for (int rg = 0; rg < 4; rg++) {
                int row = tm + wm * 32 + mi * 16 + quad * 4 + rg;
                int col = tn + wn * 32 + ni * 16 + l15;
                C[(size_t)row * N + col] = acc[mi][ni][rg];
            }
}

// ---------------- launch ----------------
extern "C" void kernel_launch(void* const* d_in, const int* in_sizes, int n_in,
                              void* d_out, int out_size, void* d_ws, size_t ws_size,
                              hipStream_t stream)
{
    const float* X  = (const float*)d_in[0];
    const float* Wq = (const float*)d_in[1];
    const float* Wk = (const float*)d_in[2];
    const float* Wv = (const float*)d_in[3];
    const float* Wo = (const float*)d_in[4];
    const int* tpos = (const int*)d_in[5];
    float* out = (float*)d_out;
    char* ws = (char*)d_ws;

    const size_t MB = (size_t)1 << 20;
    u16*    Xb  = (u16*)(ws + 0);        // 8 MB bf16 X
    u16*    WqB = (u16*)(ws + 8 * MB);
    u16*    WkB = (u16*)(ws + 10 * MB);
    u16*    WvB = (u16*)(ws + 12 * MB);
    u16*    WoB = (u16*)(ws + 14 * MB);
    float2* tab = (float2*)(ws + 16 * MB);  // 512 KB rope table (j-major)
    u16*    Qt  = (u16*)(ws + 24 * MB);
    u16*    Kt  = (u16*)(ws + 32 * MB);
    u16*    Vt  = (u16*)(ws + 40 * MB);
    u16*   AOut = (u16*)(ws + 48 * MB);

    cvt_all<<<dim3(1024, 9), 256, 0, stream>>>(X, Wq, Wk, Wv, Wo, tpos,
                                               Xb, WqB, WkB, WvB, WoB, tab);

    gemm_qkv<<<dim3(16, 4, 3), 512, 0, stream>>>(Xb, WqB, WkB, WvB,
                                                 Qt, Kt, Vt, tab);
    attn_kernel<<<dim3(1024, 1, 1), 256, 0, stream>>>(Qt, Kt, Vt, AOut);
    gemm_o<<<dim3(64, 16), 256, 0, stream>>>(AOut, WoB, out);
}

// Round 13
// 174.374 us; speedup vs baseline: 1.1042x; 1.1042x over previous
//
#include <hip/hip_runtime.h>
#include <hip/hip_bf16.h>
#include <hip/hip_cooperative_groups.h>

#define D_MODEL 1024
#define NHEAD   16
#define HDIM    64
#define SEQQ    2048
#define NBATCH  2
#define MROWS   (NBATCH * SEQQ)   // 4096

typedef unsigned short u16;
typedef __attribute__((ext_vector_type(8))) short short8;    // 8 bf16 (4 VGPRs)
typedef __attribute__((ext_vector_type(4))) short bf16x4;    // 4 bf16 (2 VGPRs)
typedef __attribute__((ext_vector_type(4))) float floatx4;   // 4 fp32

__device__ __forceinline__ u16 f2b(float f) {
    union { __hip_bfloat16 h; u16 u; } cv;
    cv.h = __float2bfloat16(f);
    return cv.u;
}
__device__ __forceinline__ float b2f(u16 u) {
    return __uint_as_float(((unsigned int)u) << 16);
}
__device__ __forceinline__ short8 load8(const u16* p) {
    return *reinterpret_cast<const short8*>(p);
}
__device__ __forceinline__ bf16x4 load4v(const u16* p) {
    return *reinterpret_cast<const bf16x4*>(p);
}
__device__ __forceinline__ unsigned pack2(float lo, float hi) {
    return ((unsigned)f2b(hi) << 16) | (unsigned)f2b(lo);
}
__device__ __forceinline__ void async_cp16(const void* g, void* l) {
    __builtin_amdgcn_global_load_lds(
        (const __attribute__((address_space(1))) void*)g,
        (__attribute__((address_space(3))) void*)l, 16, 0, 0);
}

// ================= phase bodies (shared by mega + standalone fallback) =================

// ---- cvt: z 0..3 X quarters; 4..5 Wq/Wk de-interleaved; 6..7 Wv/Wo; 8 rope table ----
__device__ __forceinline__ void cvt_body(
    int bx, int zz, int tid,
    const float* X, const float* Wq, const float* Wk, const float* Wv,
    const float* Wo, const int* pos,
    u16* Xb, u16* WqB, u16* WkB, u16* WvB, u16* WoB, float2* tab)
{
    const int i = bx * 256 + tid;
    if (zz == 8) {
        if (i < SEQQ * 32) {
            const int j = i >> 11, s = i & (SEQQ - 1);
            const float p = (float)pos[s];
            const float inv = expf(-(float)j * (9.210340371976184f / 32.0f));
            float sn, cs;
            sincosf(p * inv, &sn, &cs);
            tab[i] = make_float2(cs, sn);
        }
        return;
    }
    const int n4 = (D_MODEL * D_MODEL) / 4;
    const float* in;
    u16* outp;
    if (zz < 4) { in = X + (size_t)zz * n4 * 4;  outp = Xb + (size_t)zz * n4 * 4; }
    else {
        in   = (zz == 4) ? Wq : (zz == 5) ? Wk : (zz == 6) ? Wv : Wo;
        outp = (zz == 4) ? WqB : (zz == 5) ? WkB : (zz == 6) ? WvB : WoB;
    }
    int src = i;
    if (zz == 4 || zz == 5) {
        const int orow = i >> 8;
        const int g    = i & 255;
        const int irow = (orow & ~63) | (((orow & 31) << 1) | ((orow >> 5) & 1));
        src = irow * 256 + g;
    }
    float4 v = reinterpret_cast<const float4*>(in)[src];
    ushort4 o;
    o.x = f2b(v.x); o.y = f2b(v.y); o.z = f2b(v.z); o.w = f2b(v.w);
    reinterpret_cast<ushort4*>(outp)[i] = o;
}

// ---- QKV GEMM (R7-best: 128x128 tile, dbuf, single barrier, fused rope/V epilogue) ----
// smem layout: As[2] at 0 (2x4096 u16), Bs[2] at 8192. 32 KB total.
__device__ __forceinline__ void qkv_body(
    int bid, int tid, u16* smem,
    const u16* A, const u16* B0, const u16* B1, const u16* B2,
    u16* Qt, u16* Kt, u16* Vt, const float2* tab)
{
    const int K = D_MODEL;
    const int z  = bid >> 8;          // grid (32,8,3), x fastest
    const int bx = bid & 31;
    const int by = (bid >> 5) & 7;
    const u16* Bt = (z == 0) ? B0 : (z == 1 ? B1 : B2);

    const int w    = tid >> 6;
    const int lane = tid & 63;
    const int l15  = lane & 15;
    const int quad = lane >> 4;
    const int wm   = w >> 1, wn = w & 1;
    const int tm   = bx * 128, tn = by * 128;

    floatx4 acc[4][4];
#pragma unroll
    for (int i = 0; i < 4; i++)
#pragma unroll
        for (int j = 0; j < 4; j++) {
            floatx4 zz4 = {0.f, 0.f, 0.f, 0.f};
            acc[i][j] = zz4;
        }

    const int srow = lane >> 2;
    const int scol = (lane & 3) * 8;

    auto stage = [&](int buf, int k0) {
#pragma unroll
        for (int ch = w; ch < 8; ch += 4) {
            async_cp16(A  + (size_t)(tm + ch * 16 + srow) * K + k0 + scol,
                       smem + buf * 4096 + ch * 512);
            async_cp16(Bt + (size_t)(tn + ch * 16 + srow) * K + k0 + scol,
                       smem + 8192 + buf * 4096 + ch * 512);
        }
    };

    stage(0, 0);

    for (int kt = 0; kt < 32; ++kt) {
        asm volatile("s_waitcnt vmcnt(0)" ::: "memory");
        __builtin_amdgcn_s_barrier();
        if (kt < 31) stage((kt + 1) & 1, (kt + 1) * 32);

        const u16* AsB = smem + (kt & 1) * 4096;
        const u16* BsB = smem + 8192 + (kt & 1) * 4096;

        short8 af[4], bfr[4];
#pragma unroll
        for (int mi = 0; mi < 4; mi++)
            af[mi] = load8(&AsB[(wm * 64 + mi * 16 + l15) * 32 + quad * 8]);
#pragma unroll
        for (int ni = 0; ni < 4; ni++)
            bfr[ni] = load8(&BsB[(wn * 64 + ni * 16 + l15) * 32 + quad * 8]);
#pragma unroll
        for (int mi = 0; mi < 4; mi++)
#pragma unroll
            for (int ni = 0; ni < 4; ni++)
                acc[mi][ni] = __builtin_amdgcn_mfma_f32_16x16x32_bf16(af[mi], bfr[ni], acc[mi][ni], 0, 0, 0);
    }

    if (z == 2) {
        // V: write transposed [b,h,d,s]; 4 rg = 4 consecutive s, one 8B store
#pragma unroll
        for (int mi = 0; mi < 4; mi++) {
            const int r0 = tm + wm * 64 + mi * 16 + quad * 4;
            const int bb = r0 >> 11, s0 = r0 & (SEQQ - 1);
#pragma unroll
            for (int ni = 0; ni < 4; ni++) {
                const int colb = tn + wn * 64 + ni * 16 + l15;
                const int d = colb & 63, hh = colb >> 6;
                ushort4 pk;
                pk.x = f2b(acc[mi][ni][0]);
                pk.y = f2b(acc[mi][ni][1]);
                pk.z = f2b(acc[mi][ni][2]);
                pk.w = f2b(acc[mi][ni][3]);
                *reinterpret_cast<ushort4*>(
                    &Vt[(((size_t)(bb * NHEAD + hh)) * HDIM + d) * SEQQ + s0]) = pk;
            }
        }
    } else {
        // Q/K rope epilogue: pipelined table loads, paired u32 stores.
        const float qsc = (z == 0) ? 0.18033688011112042f : 1.0f;  // 0.125*log2(e) | 1
        u16* Outp = (z == 0) ? Qt : Kt;
        const int hh = (tn >> 6) + wn;
        float4 ta[2], tb[2];
        auto ldtab = [&](int g) {
            const int mi = g >> 1, ni = g & 1;
            const int qq = ni * 16 + l15;
            const int s0 = (tm + wm * 64 + mi * 16 + quad * 4) & (SEQQ - 1);
            ta[g & 1] = *reinterpret_cast<const float4*>(&tab[qq * SEQQ + s0]);
            tb[g & 1] = *reinterpret_cast<const float4*>(&tab[qq * SEQQ + s0 + 2]);
        };
        ldtab(0);
#pragma unroll
        for (int g = 0; g < 8; ++g) {
            if (g < 7) ldtab(g + 1);
            const int mi = g >> 1, ni = g & 1;
            const int qq = ni * 16 + l15;
            const int r0 = tm + wm * 64 + mi * 16 + quad * 4;
            const int bb = r0 >> 11, s0 = r0 & (SEQQ - 1);
            const float4 A4 = ta[g & 1], B4 = tb[g & 1];
            const float cs[4] = {A4.x, A4.z, B4.x, B4.z};
            const float sn[4] = {A4.y, A4.w, B4.y, B4.w};
#pragma unroll
            for (int rg = 0; rg < 4; rg++) {
                const float e = acc[mi][ni][rg];
                const float o = acc[mi][ni + 2][rg];
                const unsigned val =
                    (unsigned)f2b((e * cs[rg] - o * sn[rg]) * qsc) |
                    ((unsigned)f2b((e * sn[rg] + o * cs[rg]) * qsc) << 16);
                *reinterpret_cast<unsigned*>(
                    &Outp[(((size_t)(bb * NHEAD + hh)) * SEQQ + (s0 + rg)) * HDIM + 2 * qq]) = val;
            }
        }
    }
}

// ---- attn v13 (balanced 1024-block map, dbuf K/V, in-register P, setprio) ----
// smem layout: Ks[2] at 0 (2x4096), Vs[2] at 8192. 32 KB total.
__device__ __forceinline__ void attn_body(
    int bid, int tid, u16* smem,
    const u16* Qt, const u16* Kt, const u16* Vt, u16* Out)
{
    const int xcd = bid & 7;
    const int u   = bid >> 3;
    const int col = xcd * 4 + (u & 3);
    const int m   = u >> 2;
    int qsub;
    if      (m < 8)  qsub = 31 - m;
    else if (m < 16) qsub = m - 8;
    else if (m < 24) qsub = 39 - m;
    else             qsub = m - 16;
    const int h = col & (NHEAD - 1), b = col >> 4;

    const int w = tid >> 6, lane = tid & 63;
    const int l15 = lane & 15, quad = lane >> 4;
    const size_t bh = (size_t)(b * NHEAD + h);
    const u16* Qh = Qt + bh * SEQQ * HDIM;
    const u16* Kh = Kt + bh * SEQQ * HDIM;
    const u16* Vh = Vt + bh * HDIM * SEQQ;   // [d][s]

    short8 ones;
#pragma unroll
    for (int i = 0; i < 8; i++) ones[i] = (short)0x3F80;  // bf16 1.0

    const int rr  = lane >> 3;
    const int swz = ((lane & 7) ^ rr) * 8;
    auto stage = [&](int buf, int tt) {
        const int k0s = tt * 64;
        async_cp16(Kh + (size_t)(k0s + w * 8 + rr) * HDIM + swz,       smem + buf * 4096 + w * 512);
        async_cp16(Kh + (size_t)(k0s + (w + 4) * 8 + rr) * HDIM + swz, smem + buf * 4096 + (w + 4) * 512);
        async_cp16(Vh + (size_t)(w * 8 + rr) * SEQQ + k0s + swz,       smem + 8192 + buf * 4096 + w * 512);
        async_cp16(Vh + (size_t)((w + 4) * 8 + rr) * SEQQ + k0s + swz, smem + 8192 + buf * 4096 + (w + 4) * 512);
    };

    const int s7  = l15 & 7;
    const int sw1 = ((quad)     ^ s7) * 8;
    const int sw2 = ((quad + 4) ^ s7) * 8;
    const int vo0 = (((quad >> 1)    ) ^ s7) * 8 + (quad & 1) * 4;
    const int vo1 = (((quad >> 1) + 2) ^ s7) * 8 + (quad & 1) * 4;
    const int vo2 = (((quad >> 1) + 4) ^ s7) * 8 + (quad & 1) * 4;
    const int vo3 = (((quad >> 1) + 6) ^ s7) * 8 + (quad & 1) * 4;

    const int q0w   = qsub * 64 + w * 16;
    const int tmaxp = qsub;

    short8 qf[2];
#pragma unroll
    for (int kk = 0; kk < 2; kk++)
        qf[kk] = load8(&Qh[(size_t)(q0w + l15) * HDIM + kk * 32 + quad * 8]);

    floatx4 O[4];
    floatx4 l_acc = {0.f, 0.f, 0.f, 0.f};
#pragma unroll
    for (int c = 0; c < 4; c++) { floatx4 zz4 = {0.f, 0.f, 0.f, 0.f}; O[c] = zz4; }

    stage(0, 0);

    for (int t = 0; t <= tmaxp; ++t) {
        asm volatile("s_waitcnt vmcnt(0)" ::: "memory");
        __builtin_amdgcn_s_barrier();
        if (t < tmaxp) stage((t + 1) & 1, t + 1);

        const u16* KsB = smem + (t & 1) * 4096;
        const u16* VsB = smem + 8192 + (t & 1) * 4096;
        const int k0 = t * 64;

        floatx4 S[4];
        __builtin_amdgcn_s_setprio(1);
#pragma unroll
        for (int c = 0; c < 4; c++) {
            const int rowb = (c * 16 + l15) * 64;
            floatx4 zz4 = {0.f, 0.f, 0.f, 0.f};
            S[c] = __builtin_amdgcn_mfma_f32_16x16x32_bf16(load8(&KsB[rowb + sw1]), qf[0], zz4, 0, 0, 0);
            S[c] = __builtin_amdgcn_mfma_f32_16x16x32_bf16(load8(&KsB[rowb + sw2]), qf[1], S[c], 0, 0, 0);
        }
        __builtin_amdgcn_s_setprio(0);

        if (t == tmaxp) {
            const int q = q0w + l15;
#pragma unroll
            for (int c = 0; c < 4; c++)
#pragma unroll
                for (int r = 0; r < 4; r++)
                    if (k0 + c * 16 + quad * 4 + r > q) S[c][r] = -1e30f;
        }

#pragma unroll
        for (int c = 0; c < 4; c++)
#pragma unroll
            for (int r = 0; r < 4; r++)
                S[c][r] = __builtin_amdgcn_exp2f(S[c][r]);

        union { short8 v; unsigned u2[4]; } pf0, pf1;
        pf0.u2[0] = pack2(S[0][0], S[0][1]);
        pf0.u2[1] = pack2(S[0][2], S[0][3]);
        pf0.u2[2] = pack2(S[1][0], S[1][1]);
        pf0.u2[3] = pack2(S[1][2], S[1][3]);
        pf1.u2[0] = pack2(S[2][0], S[2][1]);
        pf1.u2[1] = pack2(S[2][2], S[2][3]);
        pf1.u2[2] = pack2(S[3][0], S[3][1]);
        pf1.u2[3] = pack2(S[3][2], S[3][3]);

        __builtin_amdgcn_s_setprio(1);
        l_acc = __builtin_amdgcn_mfma_f32_16x16x32_bf16(pf0.v, ones, l_acc, 0, 0, 0);
        l_acc = __builtin_amdgcn_mfma_f32_16x16x32_bf16(pf1.v, ones, l_acc, 0, 0, 0);

#pragma unroll
        for (int c2 = 0; c2 < 4; c2++) {
            const int rowb = (c2 * 16 + l15) * 64;
            bf16x4 a0 = load4v(&VsB[rowb + vo0]);
            bf16x4 a1 = load4v(&VsB[rowb + vo1]);
            bf16x4 a2 = load4v(&VsB[rowb + vo2]);
            bf16x4 a3 = load4v(&VsB[rowb + vo3]);
            short8 v0 = __builtin_shufflevector(a0, a1, 0, 1, 2, 3, 4, 5, 6, 7);
            short8 v1 = __builtin_shufflevector(a2, a3, 0, 1, 2, 3, 4, 5, 6, 7);
            O[c2] = __builtin_amdgcn_mfma_f32_16x16x32_bf16(pf0.v, v0, O[c2], 0, 0, 0);
            O[c2] = __builtin_amdgcn_mfma_f32_16x16x32_bf16(pf1.v, v1, O[c2], 0, 0, 0);
        }
        __builtin_amdgcn_s_setprio(0);
    }

    float inv_l[4];
#pragma unroll
    for (int r = 0; r < 4; r++) inv_l[r] = 1.0f / l_acc[r];

#pragma unroll
    for (int c2 = 0; c2 < 4; c2++)
#pragma unroll
        for (int r = 0; r < 4; r++) {
            const int q    = q0w + quad * 4 + r;
            const int colo = h * HDIM + c2 * 16 + l15;
            Out[(size_t)(b * SEQQ + q) * D_MODEL + colo] = f2b(O[c2][r] * inv_l[r]);
        }
}

// ---- gemm_o (64x64 tile, 3-buf counted-vmcnt) ----
// smem layout: As[3] at 0 (3x2048), Bs[3] at 6144. 24 KB total.
__device__ __forceinline__ void gemmo_body(
    int bid, int tid, u16* smem,
    const u16* A, const u16* Bt, float* C)
{
    const int K = D_MODEL, N = D_MODEL;
    const int bx = bid & 63, by = bid >> 6;   // grid (64,16)
    const int w    = tid >> 6;
    const int lane = tid & 63;
    const int l15  = lane & 15;
    const int quad = lane >> 4;
    const int wm   = w >> 1, wn = w & 1;
    const int tm   = bx * 64, tn = by * 64;

    floatx4 acc[2][2];
#pragma unroll
    for (int i = 0; i < 2; i++)
#pragma unroll
        for (int j = 0; j < 2; j++) {
            floatx4 z4 = {0.f, 0.f, 0.f, 0.f};
            acc[i][j] = z4;
        }

    const int srow = lane >> 2;
    const int scol = (lane & 3) * 8;

    auto stage = [&](int buf, int k0) {
        async_cp16(A  + (size_t)(tm + w * 16 + srow) * K + k0 + scol, smem + buf * 2048 + w * 512);
        async_cp16(Bt + (size_t)(tn + w * 16 + srow) * K + k0 + scol, smem + 6144 + buf * 2048 + w * 512);
    };

    stage(0, 0);
    stage(1, 32);

    for (int kt = 0; kt < 32; ++kt) {
        if (kt < 30) asm volatile("s_waitcnt vmcnt(2)" ::: "memory");
        else         asm volatile("s_waitcnt vmcnt(0)" ::: "memory");
        __builtin_amdgcn_s_barrier();
        if (kt < 30) stage((kt + 2) % 3, (kt + 2) * 32);

        const u16* AsB = smem + (kt % 3) * 2048;
        const u16* BsB = smem + 6144 + (kt % 3) * 2048;

        short8 af[2], bfr[2];
#pragma unroll
        for (int mi = 0; mi < 2; mi++)
            af[mi] = load8(&AsB[(wm * 32 + mi * 16 + l15) * 32 + quad * 8]);
#pragma unroll
        for (int ni = 0; ni < 2; ni++)
            bfr[ni] = load8(&BsB[(wn * 32 + ni * 16 + l15) * 32 + quad * 8]);
#pragma unroll
        for (int mi = 0; mi < 2; mi++)
#pragma unroll
            for (int ni = 0; ni < 2; ni++)
                acc[mi][ni] = __builtin_amdgcn_mfma_f32_16x16x32_bf16(af[mi], bfr[ni], acc[mi][ni], 0, 0, 0);
    }

#pragma unroll
    for (int mi = 0; mi < 2; mi++)
#pragma unroll
        for (int ni = 0; ni < 2; ni++)
#pragma unroll
            for (int rg = 0; rg < 4; rg++) {
                int row = tm + wm * 32 + mi * 16 + quad * 4 + rg;
                int colo = tn + wn * 32 + ni * 16 + l15;
                C[(size_t)row * N + colo] = acc[mi][ni][rg];
            }
}

// ================= mega-kernel: one cooperative launch, 3 grid.syncs =================
// 1024 blocks x 256 threads, 32 KB LDS/block -> 4 blocks/CU = exactly 1024
// co-resident. Replaces 4 sequential dispatches (~10us launch overhead each).
__global__ __launch_bounds__(256, 4) void mega(
    const float* __restrict__ X,  const float* __restrict__ Wq,
    const float* __restrict__ Wk, const float* __restrict__ Wv,
    const float* __restrict__ Wo, const int* __restrict__ pos,
    u16* __restrict__ Xb,  u16* __restrict__ WqB, u16* __restrict__ WkB,
    u16* __restrict__ WvB, u16* __restrict__ WoB, float2* __restrict__ tab,
    u16* __restrict__ Qt, u16* __restrict__ Kt, u16* __restrict__ Vt,
    u16* __restrict__ AOut, float* __restrict__ out)
{
    cooperative_groups::grid_group grid = cooperative_groups::this_grid();
    __shared__ __attribute__((aligned(16))) u16 smem[16384];   // 32 KB union

    const int tid  = threadIdx.x;
    const int bid0 = blockIdx.x;

    // phase 0: convert + rope table (grid-stride 9216 virtual blocks)
    for (int vb = bid0; vb < 9216; vb += 1024)
        cvt_body(vb & 1023, vb >> 10, tid, X, Wq, Wk, Wv, Wo, pos,
                 Xb, WqB, WkB, WvB, WoB, tab);
    __threadfence();
    grid.sync();

    // phase 1: QKV GEMM + fused rope/transpose (768 tiles; blocks >=768 idle)
    if (bid0 < 768)
        qkv_body(bid0, tid, smem, Xb, WqB, WkB, WvB, Qt, Kt, Vt, tab);
    __threadfence();
    grid.sync();

    // phase 2: causal flash attention (1024 blocks exactly)
    attn_body(bid0, tid, smem, Qt, Kt, Vt, AOut);
    __threadfence();
    grid.sync();

    // phase 3: o-proj GEMM (1024 tiles exactly)
    gemmo_body(bid0, tid, smem, AOut, WoB, out);
}

// ================= standalone fallback kernels (legacy 4-dispatch path) =================
__global__ void cvt_all_k(const float* __restrict__ X,
                          const float* __restrict__ w0, const float* __restrict__ w1,
                          const float* __restrict__ w2, const float* __restrict__ w3,
                          const int* __restrict__ pos,
                          u16* __restrict__ xo,
                          u16* __restrict__ o0, u16* __restrict__ o1,
                          u16* __restrict__ o2, u16* __restrict__ o3,
                          float2* __restrict__ tab) {
    cvt_body(blockIdx.x, blockIdx.y, threadIdx.x, X, w0, w1, w2, w3, pos,
             xo, o0, o1, o2, o3, tab);
}

__global__ __launch_bounds__(256) void gemm_qkv_k(
    const u16* __restrict__ A,
    const u16* __restrict__ B0, const u16* __restrict__ B1, const u16* __restrict__ B2,
    u16* __restrict__ Qt, u16* __restrict__ Kt, u16* __restrict__ Vt,
    const float2* __restrict__ tab)
{
    __shared__ __attribute__((aligned(16))) u16 smem[16384];
    const int bid = blockIdx.x + blockIdx.y * 32 + blockIdx.z * 256;
    qkv_body(bid, threadIdx.x, smem, A, B0, B1, B2, Qt, Kt, Vt, tab);
}

__global__ __launch_bounds__(256, 4) void attn_k(
    const u16* __restrict__ Qt, const u16* __restrict__ Kt, const u16* __restrict__ Vt,
    u16* __restrict__ Out)
{
    __shared__ __attribute__((aligned(16))) u16 smem[16384];
    attn_body(blockIdx.x, threadIdx.x, smem, Qt, Kt, Vt, Out);
}

__global__ __launch_bounds__(256) void gemm_o_k(
    const u16* __restrict__ A, const u16* __restrict__ Bt, float* __restrict__ C)
{
    __shared__ __attribute__((aligned(16))) u16 smem[12288];
    gemmo_body(blockIdx.x + blockIdx.y * 64, threadIdx.x, smem, A, Bt, C);
}

// ---------------- launch ----------------
extern "C" void kernel_launch(void* const* d_in, const int* in_sizes, int n_in,
                              void* d_out, int out_size, void* d_ws, size_t ws_size,
                              hipStream_t stream)
{
    const float* X  = (const float*)d_in[0];
    const float* Wq = (const float*)d_in[1];
    const float* Wk = (const float*)d_in[2];
    const float* Wv = (const float*)d_in[3];
    const float* Wo = (const float*)d_in[4];
    const int* tpos = (const int*)d_in[5];
    float* out = (float*)d_out;
    char* ws = (char*)d_ws;

    const size_t MB = (size_t)1 << 20;
    u16*    Xb  = (u16*)(ws + 0);        // 8 MB bf16 X
    u16*    WqB = (u16*)(ws + 8 * MB);
    u16*    WkB = (u16*)(ws + 10 * MB);
    u16*    WvB = (u16*)(ws + 12 * MB);
    u16*    WoB = (u16*)(ws + 14 * MB);
    float2* tab = (float2*)(ws + 16 * MB);  // 512 KB rope table (j-major)
    u16*    Qt  = (u16*)(ws + 24 * MB);
    u16*    Kt  = (u16*)(ws + 32 * MB);
    u16*    Vt  = (u16*)(ws + 40 * MB);
    u16*   AOut = (u16*)(ws + 48 * MB);

    static int use_coop = -1;
    if (use_coop < 0) {
        int nb = 0;
        hipError_t e = hipOccupancyMaxActiveBlocksPerMultiprocessor(
            &nb, reinterpret_cast<const void*>(&mega), 256, 0);
        int dev = 0, coop = 0;
        hipGetDevice(&dev);
        hipDeviceGetAttribute(&coop, hipDeviceAttributeCooperativeLaunch, dev);
        use_coop = (e == hipSuccess && nb >= 4 && coop) ? 1 : 0;
    }

    if (use_coop) {
        void* args[] = {
            (void*)&X, (void*)&Wq, (void*)&Wk, (void*)&Wv, (void*)&Wo, (void*)&tpos,
            (void*)&Xb, (void*)&WqB, (void*)&WkB, (void*)&WvB, (void*)&WoB, (void*)&tab,
            (void*)&Qt, (void*)&Kt, (void*)&Vt, (void*)&AOut, (void*)&out
        };
        hipLaunchCooperativeKernel(reinterpret_cast<const void*>(&mega),
                                   dim3(1024), dim3(256), args, 0, stream);
    } else {
        cvt_all_k<<<dim3(1024, 9), 256, 0, stream>>>(X, Wq, Wk, Wv, Wo, tpos,
                                                     Xb, WqB, WkB, WvB, WoB, tab);
        gemm_qkv_k<<<dim3(32, 8, 3), 256, 0, stream>>>(Xb, WqB, WkB, WvB,
                                                       Qt, Kt, Vt, tab);
        attn_k<<<dim3(1024, 1, 1), 256, 0, stream>>>(Qt, Kt, Vt, AOut);
        gemm_o_k<<<dim3(64, 16), 256, 0, stream>>>(AOut, WoB, out);
    }
}

// Round 14
// 174.367 us; speedup vs baseline: 1.1042x; 1.0000x over previous
//
#include <hip/hip_runtime.h>
#include <hip/hip_bf16.h>
#include <hip/hip_cooperative_groups.h>

#define D_MODEL 1024
#define NHEAD   16
#define HDIM    64
#define SEQQ    2048
#define NBATCH  2
#define MROWS   (NBATCH * SEQQ)   // 4096

typedef unsigned short u16;
typedef __attribute__((ext_vector_type(8))) short short8;    // 8 bf16 (4 VGPRs)
typedef __attribute__((ext_vector_type(4))) short bf16x4;    // 4 bf16 (2 VGPRs)
typedef __attribute__((ext_vector_type(4))) float floatx4;   // 4 fp32

__device__ __forceinline__ u16 f2b(float f) {
    union { __hip_bfloat16 h; u16 u; } cv;
    cv.h = __float2bfloat16(f);
    return cv.u;
}
__device__ __forceinline__ float b2f(u16 u) {
    return __uint_as_float(((unsigned int)u) << 16);
}
__device__ __forceinline__ short8 load8(const u16* p) {
    return *reinterpret_cast<const short8*>(p);
}
__device__ __forceinline__ bf16x4 load4v(const u16* p) {
    return *reinterpret_cast<const bf16x4*>(p);
}
__device__ __forceinline__ unsigned pack2(float lo, float hi) {
    return ((unsigned)f2b(hi) << 16) | (unsigned)f2b(lo);
}
__device__ __forceinline__ void async_cp16(const void* g, void* l) {
    __builtin_amdgcn_global_load_lds(
        (const __attribute__((address_space(1))) void*)g,
        (__attribute__((address_space(3))) void*)l, 16, 0, 0);
}

// ================= phase bodies (shared by mega + standalone fallback) =================

// ---- cvt: z 0..3 X quarters; 4..5 Wq/Wk de-interleaved; 6..7 Wv/Wo; 8 rope table ----
__device__ __forceinline__ void cvt_body(
    int bx, int zz, int tid,
    const float* X, const float* Wq, const float* Wk, const float* Wv,
    const float* Wo, const int* pos,
    u16* Xb, u16* WqB, u16* WkB, u16* WvB, u16* WoB, float2* tab)
{
    const int i = bx * 256 + tid;
    if (zz == 8) {
        if (i < SEQQ * 32) {
            const int j = i >> 11, s = i & (SEQQ - 1);
            const float p = (float)pos[s];
            const float inv = expf(-(float)j * (9.210340371976184f / 32.0f));
            float sn, cs;
            sincosf(p * inv, &sn, &cs);
            tab[i] = make_float2(cs, sn);
        }
        return;
    }
    const int n4 = (D_MODEL * D_MODEL) / 4;
    const float* in;
    u16* outp;
    if (zz < 4) { in = X + (size_t)zz * n4 * 4;  outp = Xb + (size_t)zz * n4 * 4; }
    else {
        in   = (zz == 4) ? Wq : (zz == 5) ? Wk : (zz == 6) ? Wv : Wo;
        outp = (zz == 4) ? WqB : (zz == 5) ? WkB : (zz == 6) ? WvB : WoB;
    }
    int src = i;
    if (zz == 4 || zz == 5) {
        const int orow = i >> 8;
        const int g    = i & 255;
        const int irow = (orow & ~63) | (((orow & 31) << 1) | ((orow >> 5) & 1));
        src = irow * 256 + g;
    }
    float4 v = reinterpret_cast<const float4*>(in)[src];
    ushort4 o;
    o.x = f2b(v.x); o.y = f2b(v.y); o.z = f2b(v.z); o.w = f2b(v.w);
    reinterpret_cast<ushort4*>(outp)[i] = o;
}

// ---- QKV GEMM (128x128 tile, dbuf, single barrier, fused rope/V epilogue) ----
// smem layout: As[2] at 0 (2x4096 u16), Bs[2] at 8192. 32 KB total.
__device__ __forceinline__ void qkv_body(
    int bid, int tid, u16* smem,
    const u16* A, const u16* B0, const u16* B1, const u16* B2,
    u16* Qt, u16* Kt, u16* Vt, const float2* tab)
{
    const int K = D_MODEL;
    const int z  = bid >> 8;          // grid (32,8,3), x fastest
    const int bx = bid & 31;
    const int by = (bid >> 5) & 7;
    const u16* Bt = (z == 0) ? B0 : (z == 1 ? B1 : B2);

    const int w    = tid >> 6;
    const int lane = tid & 63;
    const int l15  = lane & 15;
    const int quad = lane >> 4;
    const int wm   = w >> 1, wn = w & 1;
    const int tm   = bx * 128, tn = by * 128;

    floatx4 acc[4][4];
#pragma unroll
    for (int i = 0; i < 4; i++)
#pragma unroll
        for (int j = 0; j < 4; j++) {
            floatx4 zz4 = {0.f, 0.f, 0.f, 0.f};
            acc[i][j] = zz4;
        }

    const int srow = lane >> 2;
    const int scol = (lane & 3) * 8;

    auto stage = [&](int buf, int k0) {
#pragma unroll
        for (int ch = w; ch < 8; ch += 4) {
            async_cp16(A  + (size_t)(tm + ch * 16 + srow) * K + k0 + scol,
                       smem + buf * 4096 + ch * 512);
            async_cp16(Bt + (size_t)(tn + ch * 16 + srow) * K + k0 + scol,
                       smem + 8192 + buf * 4096 + ch * 512);
        }
    };

    stage(0, 0);

    for (int kt = 0; kt < 32; ++kt) {
        asm volatile("s_waitcnt vmcnt(0)" ::: "memory");
        __builtin_amdgcn_s_barrier();
        if (kt < 31) stage((kt + 1) & 1, (kt + 1) * 32);

        const u16* AsB = smem + (kt & 1) * 4096;
        const u16* BsB = smem + 8192 + (kt & 1) * 4096;

        short8 af[4], bfr[4];
#pragma unroll
        for (int mi = 0; mi < 4; mi++)
            af[mi] = load8(&AsB[(wm * 64 + mi * 16 + l15) * 32 + quad * 8]);
#pragma unroll
        for (int ni = 0; ni < 4; ni++)
            bfr[ni] = load8(&BsB[(wn * 64 + ni * 16 + l15) * 32 + quad * 8]);
#pragma unroll
        for (int mi = 0; mi < 4; mi++)
#pragma unroll
            for (int ni = 0; ni < 4; ni++)
                acc[mi][ni] = __builtin_amdgcn_mfma_f32_16x16x32_bf16(af[mi], bfr[ni], acc[mi][ni], 0, 0, 0);
    }

    if (z == 2) {
        // V: write transposed [b,h,d,s]; 4 rg = 4 consecutive s, one 8B store
#pragma unroll
        for (int mi = 0; mi < 4; mi++) {
            const int r0 = tm + wm * 64 + mi * 16 + quad * 4;
            const int bb = r0 >> 11, s0 = r0 & (SEQQ - 1);
#pragma unroll
            for (int ni = 0; ni < 4; ni++) {
                const int colb = tn + wn * 64 + ni * 16 + l15;
                const int d = colb & 63, hh = colb >> 6;
                ushort4 pk;
                pk.x = f2b(acc[mi][ni][0]);
                pk.y = f2b(acc[mi][ni][1]);
                pk.z = f2b(acc[mi][ni][2]);
                pk.w = f2b(acc[mi][ni][3]);
                *reinterpret_cast<ushort4*>(
                    &Vt[(((size_t)(bb * NHEAD + hh)) * HDIM + d) * SEQQ + s0]) = pk;
            }
        }
    } else {
        // Q/K rope epilogue: pipelined table loads, paired u32 stores.
        const float qsc = (z == 0) ? 0.18033688011112042f : 1.0f;  // 0.125*log2(e) | 1
        u16* Outp = (z == 0) ? Qt : Kt;
        const int hh = (tn >> 6) + wn;
        float4 ta[2], tb[2];
        auto ldtab = [&](int g) {
            const int mi = g >> 1, ni = g & 1;
            const int qq = ni * 16 + l15;
            const int s0 = (tm + wm * 64 + mi * 16 + quad * 4) & (SEQQ - 1);
            ta[g & 1] = *reinterpret_cast<const float4*>(&tab[qq * SEQQ + s0]);
            tb[g & 1] = *reinterpret_cast<const float4*>(&tab[qq * SEQQ + s0 + 2]);
        };
        ldtab(0);
#pragma unroll
        for (int g = 0; g < 8; ++g) {
            if (g < 7) ldtab(g + 1);
            const int mi = g >> 1, ni = g & 1;
            const int qq = ni * 16 + l15;
            const int r0 = tm + wm * 64 + mi * 16 + quad * 4;
            const int bb = r0 >> 11, s0 = r0 & (SEQQ - 1);
            const float4 A4 = ta[g & 1], B4 = tb[g & 1];
            const float cs[4] = {A4.x, A4.z, B4.x, B4.z};
            const float sn[4] = {A4.y, A4.w, B4.y, B4.w};
#pragma unroll
            for (int rg = 0; rg < 4; rg++) {
                const float e = acc[mi][ni][rg];
                const float o = acc[mi][ni + 2][rg];
                const unsigned val =
                    (unsigned)f2b((e * cs[rg] - o * sn[rg]) * qsc) |
                    ((unsigned)f2b((e * sn[rg] + o * cs[rg]) * qsc) << 16);
                *reinterpret_cast<unsigned*>(
                    &Outp[(((size_t)(bb * NHEAD + hh)) * SEQQ + (s0 + rg)) * HDIM + 2 * qq]) = val;
            }
        }
    }
}

// ---- attn v13 (balanced 1024-block map, dbuf K/V, in-register P, setprio) ----
// smem layout: Ks[2] at 0 (2x4096), Vs[2] at 8192. 32 KB total.
__device__ __forceinline__ void attn_body(
    int bid, int tid, u16* smem,
    const u16* Qt, const u16* Kt, const u16* Vt, u16* Out)
{
    const int xcd = bid & 7;
    const int u   = bid >> 3;
    const int col = xcd * 4 + (u & 3);
    const int m   = u >> 2;
    int qsub;
    if      (m < 8)  qsub = 31 - m;
    else if (m < 16) qsub = m - 8;
    else if (m < 24) qsub = 39 - m;
    else             qsub = m - 16;
    const int h = col & (NHEAD - 1), b = col >> 4;

    const int w = tid >> 6, lane = tid & 63;
    const int l15 = lane & 15, quad = lane >> 4;
    const size_t bh = (size_t)(b * NHEAD + h);
    const u16* Qh = Qt + bh * SEQQ * HDIM;
    const u16* Kh = Kt + bh * SEQQ * HDIM;
    const u16* Vh = Vt + bh * HDIM * SEQQ;   // [d][s]

    short8 ones;
#pragma unroll
    for (int i = 0; i < 8; i++) ones[i] = (short)0x3F80;  // bf16 1.0

    const int rr  = lane >> 3;
    const int swz = ((lane & 7) ^ rr) * 8;
    auto stage = [&](int buf, int tt) {
        const int k0s = tt * 64;
        async_cp16(Kh + (size_t)(k0s + w * 8 + rr) * HDIM + swz,       smem + buf * 4096 + w * 512);
        async_cp16(Kh + (size_t)(k0s + (w + 4) * 8 + rr) * HDIM + swz, smem + buf * 4096 + (w + 4) * 512);
        async_cp16(Vh + (size_t)(w * 8 + rr) * SEQQ + k0s + swz,       smem + 8192 + buf * 4096 + w * 512);
        async_cp16(Vh + (size_t)((w + 4) * 8 + rr) * SEQQ + k0s + swz, smem + 8192 + buf * 4096 + (w + 4) * 512);
    };

    const int s7  = l15 & 7;
    const int sw1 = ((quad)     ^ s7) * 8;
    const int sw2 = ((quad + 4) ^ s7) * 8;
    const int vo0 = (((quad >> 1)    ) ^ s7) * 8 + (quad & 1) * 4;
    const int vo1 = (((quad >> 1) + 2) ^ s7) * 8 + (quad & 1) * 4;
    const int vo2 = (((quad >> 1) + 4) ^ s7) * 8 + (quad & 1) * 4;
    const int vo3 = (((quad >> 1) + 6) ^ s7) * 8 + (quad & 1) * 4;

    const int q0w   = qsub * 64 + w * 16;
    const int tmaxp = qsub;

    short8 qf[2];
#pragma unroll
    for (int kk = 0; kk < 2; kk++)
        qf[kk] = load8(&Qh[(size_t)(q0w + l15) * HDIM + kk * 32 + quad * 8]);

    floatx4 O[4];
    floatx4 l_acc = {0.f, 0.f, 0.f, 0.f};
#pragma unroll
    for (int c = 0; c < 4; c++) { floatx4 zz4 = {0.f, 0.f, 0.f, 0.f}; O[c] = zz4; }

    stage(0, 0);

    for (int t = 0; t <= tmaxp; ++t) {
        asm volatile("s_waitcnt vmcnt(0)" ::: "memory");
        __builtin_amdgcn_s_barrier();
        if (t < tmaxp) stage((t + 1) & 1, t + 1);

        const u16* KsB = smem + (t & 1) * 4096;
        const u16* VsB = smem + 8192 + (t & 1) * 4096;
        const int k0 = t * 64;

        floatx4 S[4];
        __builtin_amdgcn_s_setprio(1);
#pragma unroll
        for (int c = 0; c < 4; c++) {
            const int rowb = (c * 16 + l15) * 64;
            floatx4 zz4 = {0.f, 0.f, 0.f, 0.f};
            S[c] = __builtin_amdgcn_mfma_f32_16x16x32_bf16(load8(&KsB[rowb + sw1]), qf[0], zz4, 0, 0, 0);
            S[c] = __builtin_amdgcn_mfma_f32_16x16x32_bf16(load8(&KsB[rowb + sw2]), qf[1], S[c], 0, 0, 0);
        }
        __builtin_amdgcn_s_setprio(0);

        if (t == tmaxp) {
            const int q = q0w + l15;
#pragma unroll
            for (int c = 0; c < 4; c++)
#pragma unroll
                for (int r = 0; r < 4; r++)
                    if (k0 + c * 16 + quad * 4 + r > q) S[c][r] = -1e30f;
        }

#pragma unroll
        for (int c = 0; c < 4; c++)
#pragma unroll
            for (int r = 0; r < 4; r++)
                S[c][r] = __builtin_amdgcn_exp2f(S[c][r]);

        union { short8 v; unsigned u2[4]; } pf0, pf1;
        pf0.u2[0] = pack2(S[0][0], S[0][1]);
        pf0.u2[1] = pack2(S[0][2], S[0][3]);
        pf0.u2[2] = pack2(S[1][0], S[1][1]);
        pf0.u2[3] = pack2(S[1][2], S[1][3]);
        pf1.u2[0] = pack2(S[2][0], S[2][1]);
        pf1.u2[1] = pack2(S[2][2], S[2][3]);
        pf1.u2[2] = pack2(S[3][0], S[3][1]);
        pf1.u2[3] = pack2(S[3][2], S[3][3]);

        __builtin_amdgcn_s_setprio(1);
        l_acc = __builtin_amdgcn_mfma_f32_16x16x32_bf16(pf0.v, ones, l_acc, 0, 0, 0);
        l_acc = __builtin_amdgcn_mfma_f32_16x16x32_bf16(pf1.v, ones, l_acc, 0, 0, 0);

#pragma unroll
        for (int c2 = 0; c2 < 4; c2++) {
            const int rowb = (c2 * 16 + l15) * 64;
            bf16x4 a0 = load4v(&VsB[rowb + vo0]);
            bf16x4 a1 = load4v(&VsB[rowb + vo1]);
            bf16x4 a2 = load4v(&VsB[rowb + vo2]);
            bf16x4 a3 = load4v(&VsB[rowb + vo3]);
            short8 v0 = __builtin_shufflevector(a0, a1, 0, 1, 2, 3, 4, 5, 6, 7);
            short8 v1 = __builtin_shufflevector(a2, a3, 0, 1, 2, 3, 4, 5, 6, 7);
            O[c2] = __builtin_amdgcn_mfma_f32_16x16x32_bf16(pf0.v, v0, O[c2], 0, 0, 0);
            O[c2] = __builtin_amdgcn_mfma_f32_16x16x32_bf16(pf1.v, v1, O[c2], 0, 0, 0);
        }
        __builtin_amdgcn_s_setprio(0);
    }

    float inv_l[4];
#pragma unroll
    for (int r = 0; r < 4; r++) inv_l[r] = 1.0f / l_acc[r];

#pragma unroll
    for (int c2 = 0; c2 < 4; c2++)
#pragma unroll
        for (int r = 0; r < 4; r++) {
            const int q    = q0w + quad * 4 + r;
            const int colo = h * HDIM + c2 * 16 + l15;
            Out[(size_t)(b * SEQQ + q) * D_MODEL + colo] = f2b(O[c2][r] * inv_l[r]);
        }
}

// ---- gemm_o (64x64 tile, 3-buf counted-vmcnt) ----
// smem layout: As[3] at 0 (3x2048), Bs[3] at 6144. 24 KB total.
__device__ __forceinline__ void gemmo_body(
    int bid, int tid, u16* smem,
    const u16* A, const u16* Bt, float* C)
{
    const int K = D_MODEL, N = D_MODEL;
    const int bx = bid & 63, by = bid >> 6;   // grid (64,16)
    const int w    = tid >> 6;
    const int lane = tid & 63;
    const int l15  = lane & 15;
    const int quad = lane >> 4;
    const int wm   = w >> 1, wn = w & 1;
    const int tm   = bx * 64, tn = by * 64;

    floatx4 acc[2][2];
#pragma unroll
    for (int i = 0; i < 2; i++)
#pragma unroll
        for (int j = 0; j < 2; j++) {
            floatx4 z4 = {0.f, 0.f, 0.f, 0.f};
            acc[i][j] = z4;
        }

    const int srow = lane >> 2;
    const int scol = (lane & 3) * 8;

    auto stage = [&](int buf, int k0) {
        async_cp16(A  + (size_t)(tm + w * 16 + srow) * K + k0 + scol, smem + buf * 2048 + w * 512);
        async_cp16(Bt + (size_t)(tn + w * 16 + srow) * K + k0 + scol, smem + 6144 + buf * 2048 + w * 512);
    };

    stage(0, 0);
    stage(1, 32);

    for (int kt = 0; kt < 32; ++kt) {
        if (kt < 30) asm volatile("s_waitcnt vmcnt(2)" ::: "memory");
        else         asm volatile("s_waitcnt vmcnt(0)" ::: "memory");
        __builtin_amdgcn_s_barrier();
        if (kt < 30) stage((kt + 2) % 3, (kt + 2) * 32);

        const u16* AsB = smem + (kt % 3) * 2048;
        const u16* BsB = smem + 6144 + (kt % 3) * 2048;

        short8 af[2], bfr[2];
#pragma unroll
        for (int mi = 0; mi < 2; mi++)
            af[mi] = load8(&AsB[(wm * 32 + mi * 16 + l15) * 32 + quad * 8]);
#pragma unroll
        for (int ni = 0; ni < 2; ni++)
            bfr[ni] = load8(&BsB[(wn * 32 + ni * 16 + l15) * 32 + quad * 8]);
#pragma unroll
        for (int mi = 0; mi < 2; mi++)
#pragma unroll
            for (int ni = 0; ni < 2; ni++)
                acc[mi][ni] = __builtin_amdgcn_mfma_f32_16x16x32_bf16(af[mi], bfr[ni], acc[mi][ni], 0, 0, 0);
    }

#pragma unroll
    for (int mi = 0; mi < 2; mi++)
#pragma unroll
        for (int ni = 0; ni < 2; ni++)
#pragma unroll
            for (int rg = 0; rg < 4; rg++) {
                int row = tm + wm * 32 + mi * 16 + quad * 4 + rg;
                int colo = tn + wn * 32 + ni * 16 + l15;
                C[(size_t)row * N + colo] = acc[mi][ni][rg];
            }
}

// ================= mega-kernel: coop launch, 2 grid.syncs + flag-based phase 3 =================
// R13 win: coop removed launch overhead (183.9 -> 174.4). R14: delete grid.sync
// #3. Each attn block flags its (b,qsub) group done (threadfence -> syncthreads
// -> device atomicAdd); blocks then POP gemm_o tiles from a global queue
// ordered by expected readiness (qsub ascending: short attn blocks finish
// first) and spin on flags[group]==16. All 1024 blocks co-resident (coop) ->
// no deadlock; dynamic pops absorb ANY attn imbalance (early finishers take
// more o-proj tiles). Coherency basis identical to the passing phase scheme:
// first-touch-per-kernel reads + device-scope fences. Flags re-zeroed in
// phase 0 every replay (graph-safe).
__global__ __launch_bounds__(256, 4) void mega(
    const float* __restrict__ X,  const float* __restrict__ Wq,
    const float* __restrict__ Wk, const float* __restrict__ Wv,
    const float* __restrict__ Wo, const int* __restrict__ pos,
    u16* __restrict__ Xb,  u16* __restrict__ WqB, u16* __restrict__ WkB,
    u16* __restrict__ WvB, u16* __restrict__ WoB, float2* __restrict__ tab,
    u16* __restrict__ Qt, u16* __restrict__ Kt, u16* __restrict__ Vt,
    u16* __restrict__ AOut, float* __restrict__ out, int* __restrict__ flags)
{
    cooperative_groups::grid_group grid = cooperative_groups::this_grid();
    __shared__ __attribute__((aligned(16))) u16 smem[16384];   // 32 KB union
    __shared__ int s_tile;

    const int tid  = threadIdx.x;
    const int bid0 = blockIdx.x;

    // phase 0: convert + rope table; zero flags[0..63] + pop counter flags[64]
    for (int vb = bid0; vb < 9216; vb += 1024)
        cvt_body(vb & 1023, vb >> 10, tid, X, Wq, Wk, Wv, Wo, pos,
                 Xb, WqB, WkB, WvB, WoB, tab);
    if (bid0 == 0 && tid < 65) flags[tid] = 0;
    __threadfence();
    grid.sync();

    // phase 1: QKV GEMM + fused rope/transpose (768 tiles; blocks >=768 idle)
    if (bid0 < 768)
        qkv_body(bid0, tid, smem, Xb, WqB, WkB, WvB, Qt, Kt, Vt, tab);
    __threadfence();
    grid.sync();

    // phase 2: causal flash attention, then flag this block's (b,qsub) group
    attn_body(bid0, tid, smem, Qt, Kt, Vt, AOut);
    {
        const int xcd = bid0 & 7;
        const int u   = bid0 >> 3;
        const int col = xcd * 4 + (u & 3);
        const int m   = u >> 2;
        int qsub;
        if      (m < 8)  qsub = 31 - m;
        else if (m < 16) qsub = m - 8;
        else if (m < 24) qsub = 39 - m;
        else             qsub = m - 16;
        const int bb = col >> 4;
        __threadfence();              // this thread's AOut writes device-visible
        __syncthreads();              // all threads of block fenced
        if (tid == 0) atomicAdd(&flags[bb * 32 + qsub], 1);
    }

    // phase 3: dynamic o-proj; pop tiles ordered by readiness (qsub asc)
    for (;;) {
        __syncthreads();              // smem safe to reuse (attn / prev tile done)
        if (tid == 0) s_tile = atomicAdd(&flags[64], 1);
        __syncthreads();
        const int i = s_tile;
        if (i >= 1024) break;
        const int gq = i >> 4, ny = i & 15;
        const int qs = gq >> 1, bb2 = gq & 1;
        const int bx = bb2 * 32 + qs;         // AOut row-group = gemm_o bx tile
        if (tid == 0) {
            while (atomicOr(&flags[bx], 0) < 16)
                __builtin_amdgcn_s_sleep(8);
        }
        __syncthreads();
        __threadfence();              // no stale reads of freshly-flagged AOut
        gemmo_body(bx | (ny << 6), tid, smem, AOut, WoB, out);
    }
}

// ================= standalone fallback kernels (legacy 4-dispatch path) =================
__global__ void cvt_all_k(const float* __restrict__ X,
                          const float* __restrict__ w0, const float* __restrict__ w1,
                          const float* __restrict__ w2, const float* __restrict__ w3,
                          const int* __restrict__ pos,
                          u16* __restrict__ xo,
                          u16* __restrict__ o0, u16* __restrict__ o1,
                          u16* __restrict__ o2, u16* __restrict__ o3,
                          float2* __restrict__ tab) {
    cvt_body(blockIdx.x, blockIdx.y, threadIdx.x, X, w0, w1, w2, w3, pos,
             xo, o0, o1, o2, o3, tab);
}

__global__ __launch_bounds__(256) void gemm_qkv_k(
    const u16* __restrict__ A,
    const u16* __restrict__ B0, const u16* __restrict__ B1, const u16* __restrict__ B2,
    u16* __restrict__ Qt, u16* __restrict__ Kt, u16* __restrict__ Vt,
    const float2* __restrict__ tab)
{
    __shared__ __attribute__((aligned(16))) u16 smem[16384];
    const int bid = blockIdx.x + blockIdx.y * 32 + blockIdx.z * 256;
    qkv_body(bid, threadIdx.x, smem, A, B0, B1, B2, Qt, Kt, Vt, tab);
}

__global__ __launch_bounds__(256, 4) void attn_k(
    const u16* __restrict__ Qt, const u16* __restrict__ Kt, const u16* __restrict__ Vt,
    u16* __restrict__ Out)
{
    __shared__ __attribute__((aligned(16))) u16 smem[16384];
    attn_body(blockIdx.x, threadIdx.x, smem, Qt, Kt, Vt, Out);
}

__global__ __launch_bounds__(256) void gemm_o_k(
    const u16* __restrict__ A, const u16* __restrict__ Bt, float* __restrict__ C)
{
    __shared__ __attribute__((aligned(16))) u16 smem[12288];
    gemmo_body(blockIdx.x + blockIdx.y * 64, threadIdx.x, smem, A, Bt, C);
}

// ---------------- launch ----------------
extern "C" void kernel_launch(void* const* d_in, const int* in_sizes, int n_in,
                              void* d_out, int out_size, void* d_ws, size_t ws_size,
                              hipStream_t stream)
{
    const float* X  = (const float*)d_in[0];
    const float* Wq = (const float*)d_in[1];
    const float* Wk = (const float*)d_in[2];
    const float* Wv = (const float*)d_in[3];
    const float* Wo = (const float*)d_in[4];
    const int* tpos = (const int*)d_in[5];
    float* out = (float*)d_out;
    char* ws = (char*)d_ws;

    const size_t MB = (size_t)1 << 20;
    u16*    Xb  = (u16*)(ws + 0);        // 8 MB bf16 X
    u16*    WqB = (u16*)(ws + 8 * MB);
    u16*    WkB = (u16*)(ws + 10 * MB);
    u16*    WvB = (u16*)(ws + 12 * MB);
    u16*    WoB = (u16*)(ws + 14 * MB);
    float2* tab = (float2*)(ws + 16 * MB);  // 512 KB rope table (j-major)
    u16*    Qt  = (u16*)(ws + 24 * MB);
    u16*    Kt  = (u16*)(ws + 32 * MB);
    u16*    Vt  = (u16*)(ws + 40 * MB);
    u16*   AOut = (u16*)(ws + 48 * MB);
    int*  flags = (int*)(ws + 56 * MB);     // 64 group flags + 1 pop counter

    static int use_coop = -1;
    if (use_coop < 0) {
        int nb = 0;
        hipError_t e = hipOccupancyMaxActiveBlocksPerMultiprocessor(
            &nb, reinterpret_cast<const void*>(&mega), 256, 0);
        int dev = 0, coop = 0;
        hipGetDevice(&dev);
        hipDeviceGetAttribute(&coop, hipDeviceAttributeCooperativeLaunch, dev);
        use_coop = (e == hipSuccess && nb >= 4 && coop) ? 1 : 0;
    }

    if (use_coop) {
        void* args[] = {
            (void*)&X, (void*)&Wq, (void*)&Wk, (void*)&Wv, (void*)&Wo, (void*)&tpos,
            (void*)&Xb, (void*)&WqB, (void*)&WkB, (void*)&WvB, (void*)&WoB, (void*)&tab,
            (void*)&Qt, (void*)&Kt, (void*)&Vt, (void*)&AOut, (void*)&out, (void*)&flags
        };
        hipLaunchCooperativeKernel(reinterpret_cast<const void*>(&mega),
                                   dim3(1024), dim3(256), args, 0, stream);
    } else {
        cvt_all_k<<<dim3(1024, 9), 256, 0, stream>>>(X, Wq, Wk, Wv, Wo, tpos,
                                                     Xb, WqB, WkB, WvB, WoB, tab);
        gemm_qkv_k<<<dim3(32, 8, 3), 256, 0, stream>>>(Xb, WqB, WkB, WvB,
                                                       Qt, Kt, Vt, tab);
        attn_k<<<dim3(1024, 1, 1), 256, 0, stream>>>(Qt, Kt, Vt, AOut);
        gemm_o_k<<<dim3(64, 16), 256, 0, stream>>>(AOut, WoB, out);
    }
}